// Round 9
// baseline (280.016 us; speedup 1.0000x reference)
//
#include <hip/hip_runtime.h>
#include <hip/hip_fp16.h>
#include <math.h>

#define N_NODES 100000
#define N_EDGES 3200000
#define IN_DIM 11
#define HID 32
#define HID2 16
#define SCHUNK 100352   // per-array stride in ws (multiple of 128, >= N_NODES+1)
#define BINSHIFT 8
#define BINSZ 256
#define NB 391          // ceil(100000/256) bins (256 nodes each)
#define CHUNK 6144      // edges per chunk
#define NCH 521         // ceil(3200000/6144); 521*6144 = 3201024
#define NCH1 522        // cnthist row stride (incl. sentinel column)
#define FCAP 9216       // binfill LDS staging capacity (avg bin = 8184)
#define NHALF 50000     // src-half boundary for L2 phase blocking
#define GN 64           // nodes per gather block
#define GB 1563         // ceil(100000/64)

// ---------------- wave-shuffle scan utilities (wave = 64) ----------------
__device__ __forceinline__ int wincl(int v) {
    int lane = threadIdx.x & 63;
#pragma unroll
    for (int d = 1; d < 64; d <<= 1) {
        int u = __shfl_up(v, d, 64);
        v += (lane >= d) ? u : 0;
    }
    return v;
}

// exclusive prefix of v across 512 threads; wtot = LDS int[8]; 2 barriers
__device__ __forceinline__ int blkexcl512(int v, int* wtot) {
    int t = threadIdx.x, lane = t & 63, w = t >> 6;
    int inc = wincl(v);
    if (lane == 63) wtot[w] = inc;
    __syncthreads();
    if (t < 8) {
        int x = wtot[t], ix = x;
#pragma unroll
        for (int d = 1; d < 8; d <<= 1) {
            int u = __shfl_up(ix, d, 64);
            ix += (lane >= d) ? u : 0;
        }
        wtot[t] = ix - x;   // exclusive wave base
    }
    __syncthreads();
    return inc - v + wtot[w];
}

// ---------------- binned CSR build ----------------
// Pass 1: per-chunk per-bin counts -> cnthist[bin][chunk] (stride NCH1)
__global__ __launch_bounds__(256) void k_hist(const int* __restrict__ ei,
                                              int* __restrict__ cnthist) {
    __shared__ int h[NB];
    int t = threadIdx.x;
    for (int i = t; i < NB; i += 256) h[i] = 0;
    __syncthreads();
    int b0 = blockIdx.x * CHUNK;
    int n = N_EDGES - b0; if (n > CHUNK) n = CHUNK;   // always multiple of 4
    for (int e = t * 4; e < n; e += 1024) {
        int4 d4 = *(const int4*)(ei + N_EDGES + b0 + e);
        atomicAdd(&h[d4.x >> BINSHIFT], 1);
        atomicAdd(&h[d4.y >> BINSHIFT], 1);
        atomicAdd(&h[d4.z >> BINSHIFT], 1);
        atomicAdd(&h[d4.w >> BINSHIFT], 1);
    }
    __syncthreads();
    for (int i = t; i < NB; i += 256)
        cnthist[i * NCH1 + blockIdx.x] = h[i];
}

// Pass 2: per-bin exclusive scan over chunks (in-place) + sentinel column.
__global__ __launch_bounds__(256) void k_colscan(int* __restrict__ cnthist,
                                                 int* __restrict__ colsum) {
    __shared__ int wtot[4];
    int i = blockIdx.x;   // bin
    int t = threadIdx.x;
    int lane = t & 63;
    int v[4];
    int s4 = 0;
#pragma unroll
    for (int u = 0; u < 4; ++u) {
        int idx = t * 4 + u;
        v[u] = (idx < NCH) ? cnthist[i * NCH1 + idx] : 0;
        s4 += v[u];
    }
    int inc = wincl(s4);
    if (lane == 63) wtot[t >> 6] = inc;
    __syncthreads();
    if (t < 4) {
        int x = wtot[t], ix = x;
#pragma unroll
        for (int d = 1; d < 4; d <<= 1) {
            int u2 = __shfl_up(ix, d, 64);
            ix += (lane >= d) ? u2 : 0;
        }
        wtot[t] = ix - x;
    }
    __syncthreads();
    int base = inc - s4 + wtot[t >> 6];   // exclusive across 4-groups
#pragma unroll
    for (int u = 0; u < 4; ++u) {
        int idx = t * 4 + u;
        if (idx < NCH) cnthist[i * NCH1 + idx] = base;
        base += v[u];
    }
    if (t == 255) {                        // base here == bin total
        cnthist[i * NCH1 + NCH] = base;    // sentinel column
        colsum[i] = base;
    }
}

// Pass 3: scan of 391 bin totals -> binbase (single block)
__global__ __launch_bounds__(512) void k_scanbins(const int* __restrict__ colsum,
                                                  int* __restrict__ binbase) {
    __shared__ int wtot[8];
    int t = threadIdx.x;
    int v = (t < NB) ? colsum[t] : 0;
    int pre = blkexcl512(v, wtot);
    if (t < NB) binbase[t] = pre;
    if (t == 0) binbase[NB] = N_EDGES;   // sentinel
}

// Pass 4: scatter edges into bin buckets (LDS sort + clustered dump).
__global__ __launch_bounds__(512) void k_binscatter(const int* __restrict__ ei,
                                                    const int* __restrict__ binbase,
                                                    const int* __restrict__ cnthist,
                                                    unsigned* __restrict__ binbuf) {
    __shared__ unsigned       srecS[CHUNK];  // records at sorted position (24KB)
    __shared__ unsigned short sbinS[CHUNK];  // bin at sorted position     (12KB)
    __shared__ int h[NB], rl[NB], gb[NB];
    __shared__ int wtot[8];
    int t = threadIdx.x;
    int b0 = blockIdx.x * CHUNK;
    int n = N_EDGES - b0; if (n > CHUNK) n = CHUNK;
    int pre_b = 0, c = 0;
    if (t < NB) {
        pre_b = cnthist[t * NCH1 + blockIdx.x];
        c = cnthist[t * NCH1 + blockIdx.x + 1] - pre_b;
    }
    int rlv = blkexcl512(c, wtot);   // chunk-local sorted base per bin
    if (t < NB) {
        rl[t] = rlv;
        gb[t] = binbase[t] + pre_b;  // global dump base
        h[t] = 0;                    // cursor
    }
    __syncthreads();
    for (int e = t; e < n; e += 512) {
        int d = ei[N_EDGES + b0 + e];
        int s = ei[b0 + e];
        int b = d >> BINSHIFT;
        int p = rl[b] + atomicAdd(&h[b], 1);
        srecS[p] = (unsigned)s | ((unsigned)(d & (BINSZ - 1)) << 17);  // s < 2^17
        sbinS[p] = (unsigned short)b;
    }
    __syncthreads();
    for (int p = t; p < n; p += 512) {
        int b = sbinS[p];
        binbuf[gb[b] + (p - rl[b])] = srecS[p];
    }
}

// Pass 5: per-bin counting sort keyed by (dst-local, src-half) -> csr_src with
// half-A edges first per node; rowstart packs halfA count in bits [22:31].
__global__ __launch_bounds__(512) void k_binfill(const unsigned* __restrict__ binbuf,
                                                 const int* __restrict__ binbase,
                                                 int* __restrict__ rowstart,
                                                 float* __restrict__ dinv,
                                                 int* __restrict__ csr_src) {
    int bb = blockIdx.x;
    int b = bb >> 1;        // bin
    int half = bb & 1;      // node range [half*128, half*128+128)
    int t = threadIdx.x;
    __shared__ unsigned srec[FCAP];   // 36KB staging
    __shared__ int cnt[512], rloc[512], cur[512], wtot[8];
    int ebeg = binbase[b], eend = binbase[b + 1];
    int m = eend - ebeg;
    cnt[t] = 0;
    __syncthreads();
    for (int e = t; e < m; e += 512) {
        unsigned v = binbuf[ebeg + e];
        if (e < FCAP) srec[e] = v;
        int s = (int)(v & 0x1FFFFu);
        int key = (int)((v >> 17) << 1) | (s >= NHALF);
        atomicAdd(&cnt[key], 1);
    }
    __syncthreads();
    int c = cnt[t];
    int pre = blkexcl512(c, wtot);
    rloc[t] = pre;
    cur[t] = 0;
    if ((t & 1) == 0) {                 // thread 2m owns node-local m
        int mloc = t >> 1;
        int node = b * BINSZ + mloc;
        if ((mloc >> 7) == half && node < N_NODES) {
            int tot = c + cnt[t + 1];   // cnt stable since histogram barrier
            unsigned u = (unsigned)(ebeg + pre) | ((unsigned)c << 22);
            rowstart[node] = (int)u;    // base | (halfA_count << 22)
            dinv[node] = rsqrtf((float)tot + 1.0f);  // +1 self-loop
        }
    }
    if (bb == 0 && t == 0) rowstart[N_NODES] = N_EDGES;  // sentinel (cntA=0)
    __syncthreads();
    for (int e = t; e < m; e += 512) {
        unsigned vv = (e < FCAP) ? srec[e] : binbuf[ebeg + e];
        int dl = (int)(vv >> 17);
        if ((dl >> 7) == half) {
            int s = (int)(vv & 0x1FFFFu);
            int key = (dl << 1) | (s >= NHALF);
            int p = ebeg + rloc[key] + atomicAdd(&cur[key], 1);
            csr_src[p] = s;
        }
    }
}

// ---------------- dense transform 1 (write dinv-scaled fp16, interleaved [node*32+j]) -----
__global__ void k_xw1(const float* __restrict__ x, const float* __restrict__ W1,
                      const float* __restrict__ dinv, __half* __restrict__ xwh) {
    int t = blockIdx.x * blockDim.x + threadIdx.x;
    int node = t >> 5;
    int j = t & 31;
    __shared__ float sW[IN_DIM * HID];
    __shared__ float sx[8 * IN_DIM];
    for (int i = threadIdx.x; i < IN_DIM * HID; i += 256) sW[i] = W1[i];
    int base = blockIdx.x * 8;
    if (threadIdx.x < 8 * IN_DIM) sx[threadIdx.x] = x[base * IN_DIM + threadIdx.x];
    __syncthreads();
    int ln = node - base;
    float acc = 0.0f;
#pragma unroll
    for (int k = 0; k < IN_DIM; ++k)
        acc += sx[ln * IN_DIM + k] * sW[k * HID + j];
    xwh[t] = __float2half(dinv[node] * acc);
}

// ---------------- wide edge gather (octet decomposition; range form) ----------------
__device__ __forceinline__ void accum8(float* __restrict__ acc, const uint4 v) {
    float2 f0 = __half22float2(*(const __half2*)&v.x);
    float2 f1 = __half22float2(*(const __half2*)&v.y);
    float2 f2 = __half22float2(*(const __half2*)&v.z);
    float2 f3 = __half22float2(*(const __half2*)&v.w);
    acc[0] += f0.x; acc[1] += f0.y;
    acc[2] += f1.x; acc[3] += f1.y;
    acc[4] += f2.x; acc[5] += f2.y;
    acc[6] += f3.x; acc[7] += f3.y;
}

__device__ __forceinline__ void edge_range8(int beg, int end, int q, int oj,
                                            const int* __restrict__ csr_src,
                                            const __half* __restrict__ xwh,
                                            float* __restrict__ acc) {
    int e = beg;
    for (; e + 32 <= end; e += 32) {
        int s0 = csr_src[e + q];
        int s1 = csr_src[e + 8 + q];
        int s2 = csr_src[e + 16 + q];
        int s3 = csr_src[e + 24 + q];
        uint4 v0 = *(const uint4*)(xwh + ((s0 << 5) | oj));
        uint4 v1 = *(const uint4*)(xwh + ((s1 << 5) | oj));
        uint4 v2 = *(const uint4*)(xwh + ((s2 << 5) | oj));
        uint4 v3 = *(const uint4*)(xwh + ((s3 << 5) | oj));
        accum8(acc, v0); accum8(acc, v1); accum8(acc, v2); accum8(acc, v3);
    }
    if (e + 16 <= end) {
        int s0 = csr_src[e + q];
        int s1 = csr_src[e + 8 + q];
        uint4 v0 = *(const uint4*)(xwh + ((s0 << 5) | oj));
        uint4 v1 = *(const uint4*)(xwh + ((s1 << 5) | oj));
        accum8(acc, v0); accum8(acc, v1);
        e += 16;
    }
    if (e + 8 <= end) {
        int s0 = csr_src[e + q];
        uint4 v0 = *(const uint4*)(xwh + ((s0 << 5) | oj));
        accum8(acc, v0);
        e += 8;
    }
    if (e + q < end) {  // masked tail
        int s0 = csr_src[e + q];
        uint4 v0 = *(const uint4*)(xwh + ((s0 << 5) | oj));
        accum8(acc, v0);
    }
}

__device__ __forceinline__ void octet_reduce(float* __restrict__ acc) {
#pragma unroll
    for (int m2 = 4; m2 <= 16; m2 <<= 1) {
#pragma unroll
        for (int k = 0; k < 8; ++k) acc[k] += __shfl_xor(acc[k], m2);
    }
}

// ---------------- layer-1 gather (phase-blocked) fused with bias1+relu+W2 ---------------
// 1563 blocks x 64 nodes, all co-resident: pass A gathers src<NHALF for all 8
// rounds (XWH low half hot in L2), pass B gathers src>=NHALF + dense epilogue.
__global__ __launch_bounds__(256) void k_gather_xw2(const int* __restrict__ rowstart,
                                                    const float* __restrict__ dinv,
                                                    const int* __restrict__ csr_src,
                                                    const __half* __restrict__ xwh1,
                                                    const float* __restrict__ b1,
                                                    const float* __restrict__ W2,
                                                    __half* __restrict__ xwh2) {
    __shared__ float sW2[HID * HID];
    __shared__ float stash[8][8][33];   // [round][group][j] pass-A partials
    __shared__ float sH[8][33];
    for (int i = threadIdx.x; i < HID * HID; i += 256) sW2[i] = W2[i];

    int ln = threadIdx.x >> 5;
    int l = threadIdx.x & 31;
    int q = l >> 2;
    int oj = (l & 3) << 3;
    int base = blockIdx.x * GN;

#pragma unroll 1
    for (int i = 0; i < 8; ++i) {       // ---- pass A ----
        int node = base + i * 8 + ln;
        unsigned v0 = (node < N_NODES) ? (unsigned)rowstart[node] : 0u;
        int rs = (int)(v0 & 0x3FFFFFu);
        int mid = rs + (int)(v0 >> 22);
        float acc[8];
#pragma unroll
        for (int k = 0; k < 8; ++k) acc[k] = 0.0f;
        edge_range8(rs, mid, q, oj, csr_src, xwh1, acc);
        octet_reduce(acc);
        if (q == 0) {
#pragma unroll
            for (int k = 0; k < 8; ++k) stash[i][ln][oj + k] = acc[k];
        }
    }
    __syncthreads();                    // stash + sW2 visible
#pragma unroll 1
    for (int i = 0; i < 8; ++i) {       // ---- pass B + epilogue ----
        int node = base + i * 8 + ln;
        int ok = node < N_NODES;
        unsigned v0 = ok ? (unsigned)rowstart[node] : 0u;
        unsigned v1 = ok ? (unsigned)rowstart[node + 1] : 0u;
        int rs = (int)(v0 & 0x3FFFFFu);
        int mid = rs + (int)(v0 >> 22);
        int re = (int)(v1 & 0x3FFFFFu);
        float acc[8];
#pragma unroll
        for (int k = 0; k < 8; ++k) acc[k] = 0.0f;
        edge_range8(mid, re, q, oj, csr_src, xwh1, acc);
        octet_reduce(acc);
        if (q == 0) {
#pragma unroll
            for (int k = 0; k < 8; ++k) stash[i][ln][oj + k] += acc[k];
        }
        __syncthreads();
        float dd = ok ? dinv[node] : 0.0f;
        if (ok) {
            float hv = dd * (stash[i][ln][l] + __half2float(xwh1[node * HID + l])) + b1[l];
            sH[ln][l] = hv > 0.0f ? hv : 0.0f;
        }
        __syncthreads();
        if (ok) {
            float a2 = 0.0f;
#pragma unroll
            for (int k = 0; k < HID; ++k) a2 += sH[ln][k] * sW2[k * HID + l];
            xwh2[node * HID + l] = __float2half(dd * a2);
        }
        __syncthreads();
    }
}

// ---------------- layer-2 gather (phase-blocked) fused with bias2+relu+MLP ----------------
__global__ __launch_bounds__(256) void k_gather_mlp(const int* __restrict__ rowstart,
                                                    const float* __restrict__ dinv,
                                                    const int* __restrict__ csr_src,
                                                    const __half* __restrict__ xwh,
                                                    const float* __restrict__ b2,
                                                    const float* __restrict__ Wo1,
                                                    const float* __restrict__ bo1,
                                                    const float* __restrict__ Wo2,
                                                    const float* __restrict__ bo2,
                                                    float* __restrict__ out) {
    __shared__ float sW1[HID * HID2];
    __shared__ float sb1[HID2];
    __shared__ float sW2v[HID2];
    __shared__ float sb2[HID];
    __shared__ float stash[8][8][33];
    __shared__ float sH[8][33];
    for (int i = threadIdx.x; i < HID * HID2; i += 256) sW1[i] = Wo1[i];
    if (threadIdx.x < HID2) {
        sb1[threadIdx.x] = bo1[threadIdx.x];
        sW2v[threadIdx.x] = Wo2[threadIdx.x];
    }
    if (threadIdx.x < HID) sb2[threadIdx.x] = b2[threadIdx.x];

    int ln = threadIdx.x >> 5;
    int l = threadIdx.x & 31;
    int q = l >> 2;
    int oj = (l & 3) << 3;
    int base = blockIdx.x * GN;

#pragma unroll 1
    for (int i = 0; i < 8; ++i) {       // ---- pass A ----
        int node = base + i * 8 + ln;
        unsigned v0 = (node < N_NODES) ? (unsigned)rowstart[node] : 0u;
        int rs = (int)(v0 & 0x3FFFFFu);
        int mid = rs + (int)(v0 >> 22);
        float acc[8];
#pragma unroll
        for (int k = 0; k < 8; ++k) acc[k] = 0.0f;
        edge_range8(rs, mid, q, oj, csr_src, xwh, acc);
        octet_reduce(acc);
        if (q == 0) {
#pragma unroll
            for (int k = 0; k < 8; ++k) stash[i][ln][oj + k] = acc[k];
        }
    }
    __syncthreads();
#pragma unroll 1
    for (int i = 0; i < 8; ++i) {       // ---- pass B + epilogue ----
        int node = base + i * 8 + ln;
        int ok = node < N_NODES;
        unsigned v0 = ok ? (unsigned)rowstart[node] : 0u;
        unsigned v1 = ok ? (unsigned)rowstart[node + 1] : 0u;
        int rs = (int)(v0 & 0x3FFFFFu);
        int mid = rs + (int)(v0 >> 22);
        int re = (int)(v1 & 0x3FFFFFu);
        float acc[8];
#pragma unroll
        for (int k = 0; k < 8; ++k) acc[k] = 0.0f;
        edge_range8(mid, re, q, oj, csr_src, xwh, acc);
        octet_reduce(acc);
        if (q == 0) {
#pragma unroll
            for (int k = 0; k < 8; ++k) stash[i][ln][oj + k] += acc[k];
        }
        __syncthreads();
        if (ok) {
            float dd = dinv[node];
            float hv = dd * (stash[i][ln][l] + __half2float(xwh[node * HID + l])) + sb2[l];
            sH[ln][l] = hv > 0.0f ? hv : 0.0f;
        }
        __syncthreads();
        float val = 0.0f;
        if (ok && l < HID2) {
            float a = sb1[l];
#pragma unroll
            for (int k = 0; k < HID; ++k) a += sH[ln][k] * sW1[k * HID2 + l];
            a = a > 0.0f ? a : (expf(a) - 1.0f);  // elu alpha=1
            val = a * sW2v[l];
        }
#pragma unroll
        for (int d = 16; d >= 1; d >>= 1) val += __shfl_down(val, d, 32);
        if (ok && l == 0) out[node] = val + bo2[0];
        __syncthreads();
    }
}

extern "C" void kernel_launch(void* const* d_in, const int* in_sizes, int n_in,
                              void* d_out, int out_size, void* d_ws, size_t ws_size,
                              hipStream_t stream) {
    const float* x   = (const float*)d_in[0];
    const int*   ei  = (const int*)d_in[1];
    const float* W1  = (const float*)d_in[3];
    const float* b1  = (const float*)d_in[4];
    const float* W2  = (const float*)d_in[5];
    const float* b2  = (const float*)d_in[6];
    const float* Wo1 = (const float*)d_in[7];
    const float* bo1 = (const float*)d_in[8];
    const float* Wo2 = (const float*)d_in[9];
    const float* bo2 = (const float*)d_in[10];
    float* out = (float*)d_out;

    // ws layout (4B units):
    // colsum[512] | binbase[512] | rowstart[SCHUNK] | dinv[SCHUNK]
    // | csr_src[E] (cnthist[NB*NCH1]=204102 ints aliases here; dead before binfill writes)
    // | binbuf[E] | XWH1[N*HID fp16] | XWH2[N*HID fp16]
    int*      colsum   = (int*)d_ws;
    int*      binbase  = colsum + 512;
    int*      rowstart = binbase + 512;
    float*    dinv     = (float*)(rowstart + SCHUNK);
    int*      csr_src  = (int*)(dinv + SCHUNK);
    unsigned* binbuf   = (unsigned*)(csr_src + N_EDGES);
    __half*   XWH1     = (__half*)(binbuf + N_EDGES);
    __half*   XWH2     = XWH1 + (size_t)N_NODES * HID;
    int*      cnthist  = csr_src;   // alias: NB*NCH1 = 204102 ints << N_EDGES

    const int BT = 256;
    int gNH  = (N_NODES * HID + BT - 1) / BT;       // 12500

    // binned CSR build: hist -> colscan(+sentinel) -> binscan -> scatter -> fill
    k_hist      <<<NCH, BT, 0, stream>>>(ei, cnthist);
    k_colscan   <<<NB, BT, 0, stream>>>(cnthist, colsum);
    k_scanbins  <<<1, 512, 0, stream>>>(colsum, binbase);
    k_binscatter<<<NCH, 512, 0, stream>>>(ei, binbase, cnthist, binbuf);
    k_binfill   <<<2 * NB, 512, 0, stream>>>(binbuf, binbase, rowstart, dinv, csr_src);

    // layer 1 (+ fused W2): XWH1 = fp16(dinv.*(x@W1)); XWH2 = fp16(dinv.*(relu(gather+b1)@W2))
    k_xw1<<<gNH, BT, 0, stream>>>(x, W1, dinv, XWH1);
    k_gather_xw2<<<GB, BT, 0, stream>>>(rowstart, dinv, csr_src, XWH1, b1, W2, XWH2);

    // layer 2 + head: out = MLP(relu(dinv.*gather(XWH2) + b2))
    k_gather_mlp<<<GB, BT, 0, stream>>>(rowstart, dinv, csr_src, XWH2,
                                        b2, Wo1, bo1, Wo2, bo2, out);
}